// Round 3
// baseline (251.988 us; speedup 1.0000x reference)
//
#include <hip/hip_runtime.h>

// FTScanBasic: inclusive cumsum along axis 0 of xs[8192][4096] fp32.
// d_out layout: [0..4095] = final carry (ys[-1]), [4096..] = ys flat.
//
// Two-pass chunked scan:
//   pass1: per-chunk column sums -> partials[CHUNKS][D4] (float4) in d_ws.
//          Regular loads so xs populates the 256 MiB LLC.
//   pass2: block computes its exclusive prefix by summing predecessor
//          partial rows (L2-hot, independent, coalesced), then streams its
//          chunk (xs re-read = LLC hit) writing inclusive rows with
//          NON-TEMPORAL stores so ys doesn't evict xs from LLC.

constexpr int T_ROWS = 8192;
constexpr int D_COLS = 4096;
constexpr int D4 = D_COLS / 4;           // 1024 float4 per row
constexpr int CHUNKS = 256;
constexpr int RPC = T_ROWS / CHUNKS;     // 32 rows per chunk
constexpr int THREADS = 256;
constexpr int COL_BLOCKS = D4 / THREADS; // 4

__device__ __forceinline__ void acc4(float4& a, const float4& v) {
    a.x += v.x; a.y += v.y; a.z += v.z; a.w += v.w;
}

__device__ __forceinline__ void nt_store4(float4* p, const float4& v) {
    __builtin_nontemporal_store(v.x, &p->x);
    __builtin_nontemporal_store(v.y, &p->y);
    __builtin_nontemporal_store(v.z, &p->z);
    __builtin_nontemporal_store(v.w, &p->w);
}

__global__ __launch_bounds__(THREADS)
void scan_pass1(const float4* __restrict__ xs, float4* __restrict__ partials) {
    const int col4  = blockIdx.x * THREADS + threadIdx.x;  // 0..1023
    const int chunk = blockIdx.y;
    const float4* p = xs + (size_t)chunk * RPC * D4 + col4;
    float4 acc = make_float4(0.f, 0.f, 0.f, 0.f);
#pragma unroll 8
    for (int r = 0; r < RPC; ++r) {
        acc4(acc, p[(size_t)r * D4]);
    }
    partials[(size_t)chunk * D4 + col4] = acc;
}

__global__ __launch_bounds__(THREADS)
void scan_pass2(const float4* __restrict__ xs, const float4* __restrict__ partials,
                float4* __restrict__ ys, float4* __restrict__ carry) {
    const int col4  = blockIdx.x * THREADS + threadIdx.x;
    const int chunk = blockIdx.y;

    // Exclusive prefix: sum predecessor partial rows (independent, L2-hot).
    float4 run = make_float4(0.f, 0.f, 0.f, 0.f);
#pragma unroll 8
    for (int c = 0; c < chunk; ++c) {
        acc4(run, partials[(size_t)c * D4 + col4]);
    }

    // Stream this chunk: xs re-read should be LLC-hot; ys stores bypass LLC.
    const size_t base = (size_t)chunk * RPC * D4 + col4;
#pragma unroll 8
    for (int r = 0; r < RPC; ++r) {
        acc4(run, xs[base + (size_t)r * D4]);
        nt_store4(&ys[base + (size_t)r * D4], run);
    }

    if (chunk == CHUNKS - 1) {
        nt_store4(&carry[col4], run);   // inclusive sum of all T rows
    }
}

extern "C" void kernel_launch(void* const* d_in, const int* in_sizes, int n_in,
                              void* d_out, int out_size, void* d_ws, size_t ws_size,
                              hipStream_t stream) {
    const float4* xs = (const float4*)d_in[0];
    float* out = (float*)d_out;
    float4* carry = (float4*)out;                 // first 4096 floats
    float4* ys = (float4*)(out + D_COLS);         // 16 KiB offset, 16B-aligned
    float4* partials = (float4*)d_ws;             // CHUNKS * D4 * 16 B = 4 MiB

    dim3 grid(COL_BLOCKS, CHUNKS);                // 4 x 256 = 1024 blocks
    scan_pass1<<<grid, THREADS, 0, stream>>>(xs, partials);
    scan_pass2<<<grid, THREADS, 0, stream>>>(xs, partials, ys, carry);
}